// Round 9
// baseline (140.245 us; speedup 1.0000x reference)
//
#include <hip/hip_runtime.h>
#include <hip/hip_bf16.h>

#define B_    1024
#define N_    128
#define FEAT_ 512
#define HID_  256

typedef __bf16 bf16x8 __attribute__((ext_vector_type(8)));
typedef float  f32x4  __attribute__((ext_vector_type(4)));

__device__ __forceinline__ unsigned int f2bf(float f) {
    unsigned int u = __float_as_uint(f);
    u += 0x7fffu + ((u >> 16) & 1u);   // round-to-nearest-even
    return u >> 16;
}
__device__ __forceinline__ unsigned int pack2(float a, float b) {
    return f2bf(a) | (f2bf(b) << 16);
}

union U4V8 { uint4 u; bf16x8 v; };

// ---------------- wprep: W[512][256] -> Wt_hi/Wt_lo [256 h][512 f] bf16, swizzled ----------------
// hi = truncated bf16 (upper 16 bits), lo = RNE bf16 of (w - hi): w = hi + lo + O(2^-17).
// Layout h-major so a proj block's 16-h slice is 16 KB contiguous (DMA-able); granule
// swizzle g2 = g ^ ((h&7)<<2) identical to Mbf's (dist-proven, 0 bank conflicts).
__global__ __launch_bounds__(256) void wprep_kernel(
    const float* __restrict__ W, unsigned short* __restrict__ Wt_hi,
    unsigned short* __restrict__ Wt_lo, float* __restrict__ out)
{
    const int t = threadIdx.x;      // h
    const int g = blockIdx.x;       // granule (f = g*8 .. g*8+7)
    if (g == 0 && t == 0) out[0] = (float)(N_ - 1) * 1e-12f;   // clip residue init
    float v[8];
    #pragma unroll
    for (int j = 0; j < 8; ++j) v[j] = W[(size_t)(g * 8 + j) * HID_ + t];
    unsigned int hu[4], lu[4];
    #pragma unroll
    for (int i = 0; i < 4; ++i) {
        const unsigned int u0 = __float_as_uint(v[2 * i]);
        const unsigned int u1 = __float_as_uint(v[2 * i + 1]);
        hu[i] = (u0 >> 16) | (u1 & 0xFFFF0000u);
        const float l0 = v[2 * i]     - __uint_as_float(u0 & 0xFFFF0000u);
        const float l1 = v[2 * i + 1] - __uint_as_float(u1 & 0xFFFF0000u);
        lu[i] = pack2(l0, l1);
    }
    const int g2 = g ^ ((t & 7) << 2);
    const size_t off = (size_t)t * FEAT_ + g2 * 8;
    *(uint4*)(Wt_hi + off) = make_uint4(hu[0], hu[1], hu[2], hu[3]);
    *(uint4*)(Wt_lo + off) = make_uint4(lu[0], lu[1], lu[2], lu[3]);
}

// ---------------- prep: proj-MFMA (blocks 0..127) + conv (blocks 128..1151), 512 thr ----------------
// r6-proven configuration (136.8us best), verbatim. r7 (residency/ILP) and r8 (split)
// were both neutral -> prep is structurally bound here; dist is this round's target.
// proj: global_load_lds DMA + MFMA, 3-term hi/lo bf16 split (xp = xh@Wh + xh@Wl + xl@Wh).
// conv: 32-row tile (n, jg2), swizzled granule bf16 store, sv[32][33] + shuffles.
__global__ __launch_bounds__(512, 4) void prep_kernel(
    const float* __restrict__ x, const unsigned short* __restrict__ Wt_hi,
    const unsigned short* __restrict__ Wt_lo, const float* __restrict__ bias,
    const float* __restrict__ means, const float* __restrict__ invcov,
    float* __restrict__ xp, unsigned short* __restrict__ xbf,
    unsigned short* __restrict__ Mbf, float* __restrict__ v2,
    float* __restrict__ cpart)
{
    extern __shared__ char dyn[];               // 32 KB dynamic
    const int t = threadIdx.x;
    if (blockIdx.x < 128) {
        // ---------------- proj role ----------------
        unsigned short* Ms = (unsigned short*)dyn;   // [2 terms][16 h][512 f]
        const int pb   = blockIdx.x;
        const int bg   = pb >> 4;          // 0..7  (128-row group)
        const int ht   = pb & 15;          // 0..15 (16-h group)
        const int wave = t >> 6;
        const int lane = t & 63;
        const int q    = lane >> 4;        // 0..3
        const int l    = lane & 15;

        // DMA both W-term slices: 32 chunks of 1 KB
        #pragma unroll
        for (int i = 0; i < 4; ++i) {
            const int cc   = i * 8 + wave;             // 0..31, wave-uniform
            const int term = cc >> 4, lc = cc & 15;
            const unsigned short* s = (term ? Wt_lo : Wt_hi)
                                      + (size_t)ht * (16 * FEAT_) + lc * 512 + lane * 8;
            __builtin_amdgcn_global_load_lds(
                (const __attribute__((address_space(1))) unsigned int*)s,
                (__attribute__((address_space(3))) unsigned int*)&Ms[term * 8192 + lc * 512],
                16, 0, 0);
        }

        const int row = bg * 128 + wave * 16 + l;      // A-frag m = l (q-independent)
        const float* __restrict__ xr = x + (size_t)row * FEAT_;
        f32x4 acc = {0.f, 0.f, 0.f, 0.f};
        __syncthreads();                               // drains DMA (vmcnt)

        #pragma unroll
        for (int kk = 0; kk < 16; ++kk) {
            const float4 xa = *(const float4*)(xr + kk * 32 + q * 8);
            const float4 xb = *(const float4*)(xr + kk * 32 + q * 8 + 4);
            const float vv[8] = {xa.x, xa.y, xa.z, xa.w, xb.x, xb.y, xb.z, xb.w};
            U4V8 xh, xl;
            unsigned int hu[4], lu[4];
            #pragma unroll
            for (int i = 0; i < 4; ++i) {
                const unsigned int u0 = __float_as_uint(vv[2 * i]);
                const unsigned int u1 = __float_as_uint(vv[2 * i + 1]);
                hu[i] = (u0 >> 16) | (u1 & 0xFFFF0000u);
                const float l0 = vv[2 * i]     - __uint_as_float(u0 & 0xFFFF0000u);
                const float l1 = vv[2 * i + 1] - __uint_as_float(u1 & 0xFFFF0000u);
                lu[i] = pack2(l0, l1);
            }
            xh.u = make_uint4(hu[0], hu[1], hu[2], hu[3]);
            xl.u = make_uint4(lu[0], lu[1], lu[2], lu[3]);
            const int g2 = (((kk * 4 + q) ^ ((l & 7) << 2)) << 3);
            U4V8 bh, bl;
            bh.u = *(const uint4*)&Ms[l * FEAT_ + g2];
            bl.u = *(const uint4*)&Ms[8192 + l * FEAT_ + g2];
            acc = __builtin_amdgcn_mfma_f32_16x16x32_bf16(xh.v, bh.v, acc, 0, 0, 0);
            acc = __builtin_amdgcn_mfma_f32_16x16x32_bf16(xh.v, bl.v, acc, 0, 0, 0);
            acc = __builtin_amdgcn_mfma_f32_16x16x32_bf16(xl.v, bh.v, acc, 0, 0, 0);
        }
        // C/D: col = lane&15 = h, row = q*4 + r = b-row-in-16
        const int h  = ht * 16 + l;
        const float bb = bias[h];
        #pragma unroll
        for (int r = 0; r < 4; ++r) {
            const int ro = bg * 128 + wave * 16 + q * 4 + r;
            const float val = acc[r] + bb;
            xp [(size_t)ro * HID_ + h] = val;
            xbf[(size_t)ro * HID_ + h] = (unsigned short)f2bf(val);
        }
    } else {
        // ---------------- conv role ----------------
        float (*sv)[33] = (float (*)[33])dyn;          // [32][33]
        float* sw = (float*)(dyn + 32 * 33 * 4);       // [4]
        const int cb  = blockIdx.x - 128;  // 0..1023
        const int n   = cb >> 3;           // 0..127
        const int jg2 = cb & 7;            // 32-row group
        const float* Mn = invcov + (size_t)n * (HID_ * HID_) + (size_t)jg2 * 32 * HID_;
        const float* mu = means + (size_t)n * HID_;
        unsigned short* Mb = Mbf + (size_t)n * (HID_ * HID_) + (size_t)jg2 * 32 * HID_;
        const int gc = t & 31;             // granule column (k = gc*8 .. gc*8+7)
        const int r0 = t >> 5;             // 0..15 -> rows r0 and r0+16
        const float4 mk0 = *(const float4*)(mu + gc * 8);
        const float4 mk1 = *(const float4*)(mu + gc * 8 + 4);
        #pragma unroll
        for (int i = 0; i < 2; ++i) {
            const int row = r0 + i * 16;   // local 0..31; global j = jg2*32+row, j&7 == row&7
            const float* src = Mn + (size_t)row * HID_ + gc * 8;
            const float4 a = *(const float4*)src;
            const float4 b = *(const float4*)(src + 4);
            const int g2 = gc ^ ((row & 7) << 2);
            *(uint4*)(Mb + (size_t)row * HID_ + g2 * 8) =
                make_uint4(pack2(a.x, a.y), pack2(a.z, a.w), pack2(b.x, b.y), pack2(b.z, b.w));
            sv[row][gc] = a.x * mk0.x + a.y * mk0.y + a.z * mk0.z + a.w * mk0.w
                        + b.x * mk1.x + b.y * mk1.y + b.z * mk1.z + b.w * mk1.w;
        }
        __syncthreads();
        if (t < 256) {
            const int row = t >> 3;        // 0..31 (8 rows per wave)
            const int i0  = (t & 7) * 4;
            float v = sv[row][i0] + sv[row][i0 + 1] + sv[row][i0 + 2] + sv[row][i0 + 3];
            v += __shfl_xor(v, 1);         // reduce across the 8 gc-groups
            v += __shfl_xor(v, 2);
            v += __shfl_xor(v, 4);
            const int j = jg2 * 32 + row;
            if ((t & 7) == 0) v2[(size_t)n * HID_ + j] = 2.f * v;
            float cc = ((t & 7) == 0) ? v * mu[j] : 0.f;
            cc += __shfl_xor(cc, 8);       // sum the 8 rows of this wave
            cc += __shfl_xor(cc, 16);
            cc += __shfl_xor(cc, 32);
            if ((t & 63) == 0) sw[t >> 6] = cc;
        }
        __syncthreads();
        if (t == 0) cpart[cb] = sw[0] + sw[1] + sw[2] + sw[3];
    }
}

// ---------------- dist: p[jh][b][n] = sum_{j in half} (T[b,j] - v2[n,j]) * xp[b,j] ----------------
// r9 change: dist was LDS-READ-bound, not MFMA-bound. Old: 8 waves each re-read the
//   whole 64 KB M-half (512 KB LDS-read/block, ~10us/CU at 85 B/cy) for only ~2us of
//   MFMA. New: 256 thr (4 waves), WAVE OWNS 64 b-rows (afrag[4][8] = 128 VGPR) -> each
//   bfrag ds_read feeds 4 MFMA -> LDS traffic halved (~5us). launch_bounds(256,2)
//   grants 256-VGPR budget (no r1/r3-style spill collapse); LDS 64 KB -> 2 blocks/CU.
__global__ __launch_bounds__(256, 2) void dist_kernel(
    const float* __restrict__ xp, const unsigned short* __restrict__ xbf,
    const unsigned short* __restrict__ Mbf, const float* __restrict__ v2,
    float* __restrict__ p)
{
    extern __shared__ unsigned short Ms[];   // 128 rows x 256 el (swizzled) = 65536 B

    const int tid  = threadIdx.x;
    const int bh   = blockIdx.x;       // 0..3
    const int jh   = blockIdx.y;       // 0..1
    const int n    = blockIdx.z;       // 0..127
    const int wave = tid >> 6;         // 0..3
    const int lane = tid & 63;
    const int q    = lane >> 4;        // quad 0..3
    const int l    = lane & 15;

    // ---- DMA stage 64 KB M-half: 64 chunks of 1 KB (wave, iter) ----
    const unsigned short* src = Mbf + (size_t)n * (HID_ * HID_) + (size_t)jh * 32768;
    #pragma unroll
    for (int i = 0; i < 16; ++i) {
        const int c = i * 4 + wave;    // chunk id 0..63, wave-uniform
        __builtin_amdgcn_global_load_lds(
            (const __attribute__((address_space(1))) unsigned int*)(src + (size_t)c * 512 + lane * 8),
            (__attribute__((address_space(3))) unsigned int*)&Ms[c * 512],
            16, 0, 0);
    }

    // ---- afrag: x rows (bf16, pre-converted), full K, 4 row-blocks of 16 ----
    // A layout: A[m=lane&15][k=quad*8+j]; wave owns rows bh*256 + wave*64 .. +63
    bf16x8 afrag[4][8];
    #pragma unroll
    for (int rb = 0; rb < 4; ++rb) {
        const unsigned short* xr = xbf + (size_t)(bh * 256 + wave * 64 + rb * 16 + l) * HID_;
        #pragma unroll
        for (int kk = 0; kk < 8; ++kk)
            afrag[rb][kk] = *(const bf16x8*)(xr + kk * 32 + q * 8);
    }
    // v2 per lane per ct (j = jh*128 + ct*16 + l)
    float v2l[8];
    #pragma unroll
    for (int ct = 0; ct < 8; ++ct)
        v2l[ct] = v2[(size_t)n * HID_ + jh * 128 + ct * 16 + l];

    __syncthreads();   // drains the DMA (vmcnt) + the only barrier

    float part[16];
    #pragma unroll
    for (int i = 0; i < 16; ++i) part[i] = 0.f;

    // epilogue x source: row (bh*256 + wave*64 + rb*16 + q*4 + r), col (jh*128 + ct*16 + l)
    const size_t xbase = (size_t)(bh * 256 + wave * 64 + q * 4) * HID_ + jh * 128 + l;

    #pragma unroll
    for (int ct = 0; ct < 8; ++ct) {
        // hoist fp32 x loads for the fused epilogue
        float xl[16];
        #pragma unroll
        for (int rb = 0; rb < 4; ++rb)
            #pragma unroll
            for (int r = 0; r < 4; ++r)
                xl[rb * 4 + r] = xp[xbase + (size_t)(rb * 16 + r) * HID_ + ct * 16];

        f32x4 acc0 = {0.f,0.f,0.f,0.f}, acc1 = {0.f,0.f,0.f,0.f};
        f32x4 acc2 = {0.f,0.f,0.f,0.f}, acc3 = {0.f,0.f,0.f,0.f};
        #pragma unroll
        for (int kk = 0; kk < 8; ++kk) {
            // swizzled read: row jr=ct*16+l, granule (kk*4+q)^((l&7)<<2)  -> 2-way banks (free)
            const bf16x8 bfrag = *(const bf16x8*)&Ms[(ct * 16 + l) * HID_ +
                                                     (((kk * 4 + q) ^ ((l & 7) << 2)) << 3)];
            acc0 = __builtin_amdgcn_mfma_f32_16x16x32_bf16(afrag[0][kk], bfrag, acc0, 0, 0, 0);
            acc1 = __builtin_amdgcn_mfma_f32_16x16x32_bf16(afrag[1][kk], bfrag, acc1, 0, 0, 0);
            acc2 = __builtin_amdgcn_mfma_f32_16x16x32_bf16(afrag[2][kk], bfrag, acc2, 0, 0, 0);
            acc3 = __builtin_amdgcn_mfma_f32_16x16x32_bf16(afrag[3][kk], bfrag, acc3, 0, 0, 0);
        }
        // fused epilogue: part += (T - v2) * x   (C/D layout: col=lane&15, row=quad*4+reg)
        const float vv = v2l[ct];
        #pragma unroll
        for (int r = 0; r < 4; ++r) {
            part[r]      += (acc0[r] - vv) * xl[r];
            part[4 + r]  += (acc1[r] - vv) * xl[4 + r];
            part[8 + r]  += (acc2[r] - vv) * xl[8 + r];
            part[12 + r] += (acc3[r] - vv) * xl[12 + r];
        }
    }

    // reduce across the 16 col-lanes of each quad
    #pragma unroll
    for (int i = 0; i < 16; ++i) {
        float v = part[i];
        v += __shfl_xor(v, 1);
        v += __shfl_xor(v, 2);
        v += __shfl_xor(v, 4);
        v += __shfl_xor(v, 8);
        part[i] = v;
    }
    if (l == 0) {
        float* pb = p + (size_t)jh * (B_ * N_);
        #pragma unroll
        for (int i = 0; i < 16; ++i) {
            const int row = bh * 256 + wave * 64 + (i >> 2) * 16 + q * 4 + (i & 3);
            pb[(size_t)row * N_ + n] = part[i];
        }
    }
}

// ---------------- finalize (+fused loss): distmat = sqrt(p0 + p1 + c[n] + 1e-12),
// loss partial = sum of label-selected entries (exactly 2 per 256-thread block),
// atomicAdd'ed /B onto out[0] (pre-initialized with clip residue by wprep).
__global__ __launch_bounds__(256) void finalize_kernel(
    const float* __restrict__ p, const float* __restrict__ cpart,
    const int* __restrict__ labels, float* __restrict__ out)
{
    __shared__ float sc[128];
    __shared__ float ls[4];
    const int t = threadIdx.x;
    if (t < 128) {
        float s = 0.f;
        #pragma unroll
        for (int g = 0; g < 8; ++g) s += cpart[t * 8 + g];
        sc[t] = s;
    }
    __syncthreads();
    const int i = blockIdx.x * 256 + t;             // 0..131071
    const int n = i & (N_ - 1);
    const int b = i >> 7;
    const float d = sqrtf(p[i] + p[B_ * N_ + i] + sc[n] + 1e-12f);
    out[1 + i] = d;
    float sel = (labels[b] == n) ? d : 0.f;
    #pragma unroll
    for (int m = 1; m <= 32; m <<= 1) sel += __shfl_xor(sel, m);
    if ((t & 63) == 0) ls[t >> 6] = sel;
    __syncthreads();
    if (t == 0) atomicAdd(out, (ls[0] + ls[1] + ls[2] + ls[3]) * (1.f / (float)B_));
}

extern "C" void kernel_launch(void* const* d_in, const int* in_sizes, int n_in,
                              void* d_out, int out_size, void* d_ws, size_t ws_size,
                              hipStream_t stream) {
    const float* x      = (const float*)d_in[0];
    const int*   labels = (const int*)d_in[1];
    const float* W      = (const float*)d_in[2];
    const float* bias   = (const float*)d_in[3];
    const float* means  = (const float*)d_in[4];
    const float* invcov = (const float*)d_in[5];
    float* out = (float*)d_out;

    // workspace carve-up (19,537,920 B total — unchanged from the proven layout).
    // Wt_hi/Wt_lo ALIAS p: Wt lifetime [wprep, prep-end], p lifetime [dist, finalize-end].
    char* ws = (char*)d_ws;
    unsigned short* Mbf   = (unsigned short*)(ws);               // 16,777,216 B
    float*          xp    = (float*)         (ws + 16777216);    //  1,048,576 B
    unsigned short* xbf   = (unsigned short*)(ws + 17825792);    //    524,288 B
    float*          v2    = (float*)         (ws + 18350080);    //    131,072 B
    float*          cpart = (float*)         (ws + 18481152);    //      4,096 B
    float*          p     = (float*)         (ws + 18489344);    //  1,048,576 B
    unsigned short* Wt_hi = (unsigned short*)(ws + 18489344);    //    262,144 B (alias p)
    unsigned short* Wt_lo = (unsigned short*)(ws + 18751488);    //    262,144 B (alias p)

    constexpr int DIST_LDS = 128 * HID_ * 2;   // 65536 B dynamic LDS
    (void)hipFuncSetAttribute((const void*)dist_kernel,
                              hipFuncAttributeMaxDynamicSharedMemorySize, DIST_LDS);

    wprep_kernel<<<dim3(64), 256, 0, stream>>>(W, Wt_hi, Wt_lo, out);
    prep_kernel<<<dim3(1152), 512, 32768, stream>>>(x, Wt_hi, Wt_lo, bias, means, invcov,
                                                    xp, xbf, Mbf, v2, cpart);
    dist_kernel<<<dim3(4, 2, N_), 256, DIST_LDS, stream>>>(xp, xbf, Mbf, v2, p);
    finalize_kernel<<<dim3((B_ * N_) / 256), 256, 0, stream>>>(p, cpart, labels, out);
}

// Round 10
// 134.505 us; speedup vs baseline: 1.0427x; 1.0427x over previous
//
#include <hip/hip_runtime.h>
#include <hip/hip_bf16.h>

#define B_    1024
#define N_    128
#define FEAT_ 512
#define HID_  256

typedef __bf16 bf16x8 __attribute__((ext_vector_type(8)));
typedef float  f32x4  __attribute__((ext_vector_type(4)));

__device__ __forceinline__ unsigned int f2bf(float f) {
    unsigned int u = __float_as_uint(f);
    u += 0x7fffu + ((u >> 16) & 1u);   // round-to-nearest-even
    return u >> 16;
}
__device__ __forceinline__ unsigned int pack2(float a, float b) {
    return f2bf(a) | (f2bf(b) << 16);
}

union U4V8 { uint4 u; bf16x8 v; };

// ---------------- wprep: W[512][256] -> Wt_hi/Wt_lo [256 h][512 f] bf16, swizzled ----------------
// hi = truncated bf16 (upper 16 bits), lo = RNE bf16 of (w - hi): w = hi + lo + O(2^-17).
// Layout h-major so a proj block's 16-h slice is 16 KB contiguous (DMA-able); granule
// swizzle g2 = g ^ ((h&7)<<2) identical to Mbf's (dist-proven, 0 bank conflicts).
__global__ __launch_bounds__(256) void wprep_kernel(
    const float* __restrict__ W, unsigned short* __restrict__ Wt_hi,
    unsigned short* __restrict__ Wt_lo, float* __restrict__ out)
{
    const int t = threadIdx.x;      // h
    const int g = blockIdx.x;       // granule (f = g*8 .. g*8+7)
    if (g == 0 && t == 0) out[0] = (float)(N_ - 1) * 1e-12f;   // clip residue init
    float v[8];
    #pragma unroll
    for (int j = 0; j < 8; ++j) v[j] = W[(size_t)(g * 8 + j) * HID_ + t];
    unsigned int hu[4], lu[4];
    #pragma unroll
    for (int i = 0; i < 4; ++i) {
        const unsigned int u0 = __float_as_uint(v[2 * i]);
        const unsigned int u1 = __float_as_uint(v[2 * i + 1]);
        hu[i] = (u0 >> 16) | (u1 & 0xFFFF0000u);
        const float l0 = v[2 * i]     - __uint_as_float(u0 & 0xFFFF0000u);
        const float l1 = v[2 * i + 1] - __uint_as_float(u1 & 0xFFFF0000u);
        lu[i] = pack2(l0, l1);
    }
    const int g2 = g ^ ((t & 7) << 2);
    const size_t off = (size_t)t * FEAT_ + g2 * 8;
    *(uint4*)(Wt_hi + off) = make_uint4(hu[0], hu[1], hu[2], hu[3]);
    *(uint4*)(Wt_lo + off) = make_uint4(lu[0], lu[1], lu[2], lu[3]);
}

// ---------------- prep: proj-MFMA (blocks 0..127) + conv (blocks 128..1151), 512 thr ----------------
// r6-proven configuration (136.8us best), verbatim.
// proj: global_load_lds DMA + MFMA, 3-term hi/lo bf16 split (xp = xh@Wh + xh@Wl + xl@Wh).
// conv: 32-row tile (n, jg2), swizzled granule bf16 store, sv[32][33] + shuffles.
__global__ __launch_bounds__(512, 4) void prep_kernel(
    const float* __restrict__ x, const unsigned short* __restrict__ Wt_hi,
    const unsigned short* __restrict__ Wt_lo, const float* __restrict__ bias,
    const float* __restrict__ means, const float* __restrict__ invcov,
    float* __restrict__ xp, unsigned short* __restrict__ xbf,
    unsigned short* __restrict__ Mbf, float* __restrict__ v2,
    float* __restrict__ cpart)
{
    extern __shared__ char dyn[];               // 32 KB dynamic
    const int t = threadIdx.x;
    if (blockIdx.x < 128) {
        // ---------------- proj role ----------------
        unsigned short* Ms = (unsigned short*)dyn;   // [2 terms][16 h][512 f]
        const int pb   = blockIdx.x;
        const int bg   = pb >> 4;          // 0..7  (128-row group)
        const int ht   = pb & 15;          // 0..15 (16-h group)
        const int wave = t >> 6;
        const int lane = t & 63;
        const int q    = lane >> 4;        // 0..3
        const int l    = lane & 15;

        // DMA both W-term slices: 32 chunks of 1 KB
        #pragma unroll
        for (int i = 0; i < 4; ++i) {
            const int cc   = i * 8 + wave;             // 0..31, wave-uniform
            const int term = cc >> 4, lc = cc & 15;
            const unsigned short* s = (term ? Wt_lo : Wt_hi)
                                      + (size_t)ht * (16 * FEAT_) + lc * 512 + lane * 8;
            __builtin_amdgcn_global_load_lds(
                (const __attribute__((address_space(1))) unsigned int*)s,
                (__attribute__((address_space(3))) unsigned int*)&Ms[term * 8192 + lc * 512],
                16, 0, 0);
        }

        const int row = bg * 128 + wave * 16 + l;      // A-frag m = l (q-independent)
        const float* __restrict__ xr = x + (size_t)row * FEAT_;
        f32x4 acc = {0.f, 0.f, 0.f, 0.f};
        __syncthreads();                               // drains DMA (vmcnt)

        #pragma unroll
        for (int kk = 0; kk < 16; ++kk) {
            const float4 xa = *(const float4*)(xr + kk * 32 + q * 8);
            const float4 xb = *(const float4*)(xr + kk * 32 + q * 8 + 4);
            const float vv[8] = {xa.x, xa.y, xa.z, xa.w, xb.x, xb.y, xb.z, xb.w};
            U4V8 xh, xl;
            unsigned int hu[4], lu[4];
            #pragma unroll
            for (int i = 0; i < 4; ++i) {
                const unsigned int u0 = __float_as_uint(vv[2 * i]);
                const unsigned int u1 = __float_as_uint(vv[2 * i + 1]);
                hu[i] = (u0 >> 16) | (u1 & 0xFFFF0000u);
                const float l0 = vv[2 * i]     - __uint_as_float(u0 & 0xFFFF0000u);
                const float l1 = vv[2 * i + 1] - __uint_as_float(u1 & 0xFFFF0000u);
                lu[i] = pack2(l0, l1);
            }
            xh.u = make_uint4(hu[0], hu[1], hu[2], hu[3]);
            xl.u = make_uint4(lu[0], lu[1], lu[2], lu[3]);
            const int g2 = (((kk * 4 + q) ^ ((l & 7) << 2)) << 3);
            U4V8 bh, bl;
            bh.u = *(const uint4*)&Ms[l * FEAT_ + g2];
            bl.u = *(const uint4*)&Ms[8192 + l * FEAT_ + g2];
            acc = __builtin_amdgcn_mfma_f32_16x16x32_bf16(xh.v, bh.v, acc, 0, 0, 0);
            acc = __builtin_amdgcn_mfma_f32_16x16x32_bf16(xh.v, bl.v, acc, 0, 0, 0);
            acc = __builtin_amdgcn_mfma_f32_16x16x32_bf16(xl.v, bh.v, acc, 0, 0, 0);
        }
        // C/D: col = lane&15 = h, row = q*4 + r = b-row-in-16
        const int h  = ht * 16 + l;
        const float bb = bias[h];
        #pragma unroll
        for (int r = 0; r < 4; ++r) {
            const int ro = bg * 128 + wave * 16 + q * 4 + r;
            const float val = acc[r] + bb;
            xp [(size_t)ro * HID_ + h] = val;
            xbf[(size_t)ro * HID_ + h] = (unsigned short)f2bf(val);
        }
    } else {
        // ---------------- conv role ----------------
        float (*sv)[33] = (float (*)[33])dyn;          // [32][33]
        float* sw = (float*)(dyn + 32 * 33 * 4);       // [4]
        const int cb  = blockIdx.x - 128;  // 0..1023
        const int n   = cb >> 3;           // 0..127
        const int jg2 = cb & 7;            // 32-row group
        const float* Mn = invcov + (size_t)n * (HID_ * HID_) + (size_t)jg2 * 32 * HID_;
        const float* mu = means + (size_t)n * HID_;
        unsigned short* Mb = Mbf + (size_t)n * (HID_ * HID_) + (size_t)jg2 * 32 * HID_;
        const int gc = t & 31;             // granule column (k = gc*8 .. gc*8+7)
        const int r0 = t >> 5;             // 0..15 -> rows r0 and r0+16
        const float4 mk0 = *(const float4*)(mu + gc * 8);
        const float4 mk1 = *(const float4*)(mu + gc * 8 + 4);
        #pragma unroll
        for (int i = 0; i < 2; ++i) {
            const int row = r0 + i * 16;   // local 0..31; global j = jg2*32+row, j&7 == row&7
            const float* src = Mn + (size_t)row * HID_ + gc * 8;
            const float4 a = *(const float4*)src;
            const float4 b = *(const float4*)(src + 4);
            const int g2 = gc ^ ((row & 7) << 2);
            *(uint4*)(Mb + (size_t)row * HID_ + g2 * 8) =
                make_uint4(pack2(a.x, a.y), pack2(a.z, a.w), pack2(b.x, b.y), pack2(b.z, b.w));
            sv[row][gc] = a.x * mk0.x + a.y * mk0.y + a.z * mk0.z + a.w * mk0.w
                        + b.x * mk1.x + b.y * mk1.y + b.z * mk1.z + b.w * mk1.w;
        }
        __syncthreads();
        if (t < 256) {
            const int row = t >> 3;        // 0..31 (8 rows per wave)
            const int i0  = (t & 7) * 4;
            float v = sv[row][i0] + sv[row][i0 + 1] + sv[row][i0 + 2] + sv[row][i0 + 3];
            v += __shfl_xor(v, 1);         // reduce across the 8 gc-groups
            v += __shfl_xor(v, 2);
            v += __shfl_xor(v, 4);
            const int j = jg2 * 32 + row;
            if ((t & 7) == 0) v2[(size_t)n * HID_ + j] = 2.f * v;
            float cc = ((t & 7) == 0) ? v * mu[j] : 0.f;
            cc += __shfl_xor(cc, 8);       // sum the 8 rows of this wave
            cc += __shfl_xor(cc, 16);
            cc += __shfl_xor(cc, 32);
            if ((t & 63) == 0) sw[t >> 6] = cc;
        }
        __syncthreads();
        if (t == 0) cpart[cb] = sw[0] + sw[1] + sw[2] + sw[3];
    }
}

// ---------------- dist: p[jh][b][n] = sum_{j in half} (T[b,j] - v2[n,j]) * xp[b,j] ----------------
// Body = r2-proven 8-wave version verbatim (r9's 4-wave regressed: DMA-latency hiding
// needs the waves). r10 change: XCD-AWARE BLOCK REMAP. Old grid (bh,jh,n) was bh-fastest;
// 4 blocks sharing an M-slice round-robin onto 4 DIFFERENT XCDs (non-shared L2s) ->
// Mbf fetched ~4x from HBM (64 MB, ~10us — dist's floor). New: 1D grid, id = (s&7) +
// 8*(bh + 4*(s>>3)) where s = jh*128+n -> id%8 (the XCD) is bh-invariant -> all 4
// same-slice blocks on ONE XCD, dispatched within 24 ids -> co-resident -> 3/4 reads L2.
__global__ __launch_bounds__(512, 4) void dist_kernel(
    const float* __restrict__ xp, const unsigned short* __restrict__ xbf,
    const unsigned short* __restrict__ Mbf, const float* __restrict__ v2,
    float* __restrict__ p)
{
    extern __shared__ unsigned short Ms[];   // 128 rows x 256 el (swizzled) = 65536 B

    const int tid  = threadIdx.x;
    const int id   = blockIdx.x;       // 0..1023
    const int xcd  = id & 7;
    const int rest = id >> 3;
    const int bh   = rest & 3;         // 0..3
    const int s    = (rest >> 2) * 8 + xcd;   // 0..255 (slice id)
    const int jh   = s >> 7;           // 0..1
    const int n    = s & 127;          // 0..127
    const int wave = tid >> 6;
    const int lane = tid & 63;
    const int q    = lane >> 4;        // quad 0..3
    const int l    = lane & 15;

    // ---- DMA stage 64 KB M-half: 64 chunks of 1 KB (wave, iter) ----
    const unsigned short* src = Mbf + (size_t)n * (HID_ * HID_) + (size_t)jh * 32768;
    #pragma unroll
    for (int i = 0; i < 8; ++i) {
        const int c = i * 8 + wave;    // chunk id, wave-uniform
        __builtin_amdgcn_global_load_lds(
            (const __attribute__((address_space(1))) unsigned int*)(src + (size_t)c * 512 + lane * 8),
            (__attribute__((address_space(3))) unsigned int*)&Ms[c * 512],
            16, 0, 0);
    }

    // ---- afrag: x rows (bf16, pre-converted), full K, 2 row-blocks of 16 ----
    // A layout: A[m=lane&15][k=quad*8+j]
    bf16x8 afrag[2][8];
    #pragma unroll
    for (int rb = 0; rb < 2; ++rb) {
        const unsigned short* xr = xbf + (size_t)(bh * 256 + wave * 32 + rb * 16 + l) * HID_;
        #pragma unroll
        for (int kk = 0; kk < 8; ++kk)
            afrag[rb][kk] = *(const bf16x8*)(xr + kk * 32 + q * 8);
    }
    // v2 per lane per ct (j = jh*128 + ct*16 + l)
    float v2l[8];
    #pragma unroll
    for (int ct = 0; ct < 8; ++ct)
        v2l[ct] = v2[(size_t)n * HID_ + jh * 128 + ct * 16 + l];

    __syncthreads();   // drains the DMA (vmcnt) + the only barrier

    float part[8];
    #pragma unroll
    for (int i = 0; i < 8; ++i) part[i] = 0.f;

    // epilogue x source: row (bh*256 + wave*32 + q*4 + r + rb*16), col (jh*128 + ct*16 + l)
    const size_t xbase = (size_t)(bh * 256 + wave * 32 + q * 4) * HID_ + jh * 128 + l;

    #pragma unroll
    for (int ct = 0; ct < 8; ++ct) {
        // hoist fp32 x loads for the fused epilogue
        float xl[8];
        #pragma unroll
        for (int rb = 0; rb < 2; ++rb)
            #pragma unroll
            for (int r = 0; r < 4; ++r)
                xl[rb * 4 + r] = xp[xbase + (size_t)(rb * 16 + r) * HID_ + ct * 16];

        f32x4 acc0 = {0.f,0.f,0.f,0.f}, acc1 = {0.f,0.f,0.f,0.f};
        #pragma unroll
        for (int kk = 0; kk < 8; ++kk) {
            // swizzled read: row jr=ct*16+l, granule (kk*4+q)^((l&7)<<2)  -> 2-way banks (free)
            const bf16x8 bfrag = *(const bf16x8*)&Ms[(ct * 16 + l) * HID_ +
                                                     (((kk * 4 + q) ^ ((l & 7) << 2)) << 3)];
            acc0 = __builtin_amdgcn_mfma_f32_16x16x32_bf16(afrag[0][kk], bfrag, acc0, 0, 0, 0);
            acc1 = __builtin_amdgcn_mfma_f32_16x16x32_bf16(afrag[1][kk], bfrag, acc1, 0, 0, 0);
        }
        // fused epilogue: part += (T - v2) * x   (C/D layout: col=lane&15, row=quad*4+reg)
        const float vv = v2l[ct];
        #pragma unroll
        for (int r = 0; r < 4; ++r) {
            part[r]     += (acc0[r] - vv) * xl[r];
            part[4 + r] += (acc1[r] - vv) * xl[4 + r];
        }
    }

    // reduce across the 16 col-lanes of each quad
    #pragma unroll
    for (int i = 0; i < 8; ++i) {
        float v = part[i];
        v += __shfl_xor(v, 1);
        v += __shfl_xor(v, 2);
        v += __shfl_xor(v, 4);
        v += __shfl_xor(v, 8);
        part[i] = v;
    }
    if (l == 0) {
        float* pb = p + (size_t)jh * (B_ * N_);
        #pragma unroll
        for (int i = 0; i < 8; ++i) {
            const int row = bh * 256 + wave * 32 + (i >> 2) * 16 + q * 4 + (i & 3);
            pb[(size_t)row * N_ + n] = part[i];
        }
    }
}

// ---------------- finalize (+fused loss): distmat = sqrt(p0 + p1 + c[n] + 1e-12),
// loss partial = sum of label-selected entries (exactly 2 per 256-thread block),
// atomicAdd'ed /B onto out[0] (pre-initialized with clip residue by wprep).
__global__ __launch_bounds__(256) void finalize_kernel(
    const float* __restrict__ p, const float* __restrict__ cpart,
    const int* __restrict__ labels, float* __restrict__ out)
{
    __shared__ float sc[128];
    __shared__ float ls[4];
    const int t = threadIdx.x;
    if (t < 128) {
        float s = 0.f;
        #pragma unroll
        for (int g = 0; g < 8; ++g) s += cpart[t * 8 + g];
        sc[t] = s;
    }
    __syncthreads();
    const int i = blockIdx.x * 256 + t;             // 0..131071
    const int n = i & (N_ - 1);
    const int b = i >> 7;
    const float d = sqrtf(p[i] + p[B_ * N_ + i] + sc[n] + 1e-12f);
    out[1 + i] = d;
    float sel = (labels[b] == n) ? d : 0.f;
    #pragma unroll
    for (int m = 1; m <= 32; m <<= 1) sel += __shfl_xor(sel, m);
    if ((t & 63) == 0) ls[t >> 6] = sel;
    __syncthreads();
    if (t == 0) atomicAdd(out, (ls[0] + ls[1] + ls[2] + ls[3]) * (1.f / (float)B_));
}

extern "C" void kernel_launch(void* const* d_in, const int* in_sizes, int n_in,
                              void* d_out, int out_size, void* d_ws, size_t ws_size,
                              hipStream_t stream) {
    const float* x      = (const float*)d_in[0];
    const int*   labels = (const int*)d_in[1];
    const float* W      = (const float*)d_in[2];
    const float* bias   = (const float*)d_in[3];
    const float* means  = (const float*)d_in[4];
    const float* invcov = (const float*)d_in[5];
    float* out = (float*)d_out;

    // workspace carve-up (19,537,920 B total — unchanged from the proven layout).
    // Wt_hi/Wt_lo ALIAS p: Wt lifetime [wprep, prep-end], p lifetime [dist, finalize-end].
    char* ws = (char*)d_ws;
    unsigned short* Mbf   = (unsigned short*)(ws);               // 16,777,216 B
    float*          xp    = (float*)         (ws + 16777216);    //  1,048,576 B
    unsigned short* xbf   = (unsigned short*)(ws + 17825792);    //    524,288 B
    float*          v2    = (float*)         (ws + 18350080);    //    131,072 B
    float*          cpart = (float*)         (ws + 18481152);    //      4,096 B
    float*          p     = (float*)         (ws + 18489344);    //  1,048,576 B
    unsigned short* Wt_hi = (unsigned short*)(ws + 18489344);    //    262,144 B (alias p)
    unsigned short* Wt_lo = (unsigned short*)(ws + 18751488);    //    262,144 B (alias p)

    constexpr int DIST_LDS = 128 * HID_ * 2;   // 65536 B dynamic LDS
    (void)hipFuncSetAttribute((const void*)dist_kernel,
                              hipFuncAttributeMaxDynamicSharedMemorySize, DIST_LDS);

    wprep_kernel<<<dim3(64), 256, 0, stream>>>(W, Wt_hi, Wt_lo, out);
    prep_kernel<<<dim3(1152), 512, 32768, stream>>>(x, Wt_hi, Wt_lo, bias, means, invcov,
                                                    xp, xbf, Mbf, v2, cpart);
    dist_kernel<<<dim3(1024), 512, DIST_LDS, stream>>>(xp, xbf, Mbf, v2, p);
    finalize_kernel<<<dim3((B_ * N_) / 256), 256, 0, stream>>>(p, cpart, labels, out);
}